// Round 1
// baseline (927.735 us; speedup 1.0000x reference)
//
#include <hip/hip_runtime.h>

#define TF 8      // T (edge types)
#define FD 32     // F (features)
#define EPSV 1e-5f

__device__ __forceinline__ void atomAddF(float* p, float v) {
#if defined(__HIP_PLATFORM_AMD__)
    unsafeAtomicAdd(p, v);   // hardware global_atomic_add_f32
#else
    atomicAdd(p, v);
#endif
}

// Layer 0: h is (N, F), broadcast across T.
__global__ __launch_bounds__(256) void scatter0_kernel(
    const float* __restrict__ h, const float* __restrict__ w,
    const int* __restrict__ src, const int* __restrict__ dst,
    float* __restrict__ agg, int E)
{
    int gid = blockIdx.x * 256 + threadIdx.x;
    int e = gid >> 5;           // 32 lanes per edge
    if (e >= E) return;
    int f = gid & 31;
    int s = src[e], d = dst[e];
    float hv = h[(size_t)s * FD + f];
    float* aggd = agg + (size_t)d * (TF * FD) + f;
    #pragma unroll
    for (int t = 0; t < TF; ++t) {
        float we = w[(size_t)t * E + e];
        atomAddF(aggd + t * FD, we * hv);
    }
}

// Layers 1..: h is (N, T, F).
__global__ __launch_bounds__(256) void scatterL_kernel(
    const float* __restrict__ h, const float* __restrict__ w,
    const int* __restrict__ src, const int* __restrict__ dst,
    float* __restrict__ agg, int E)
{
    int gid = blockIdx.x * 256 + threadIdx.x;
    int e = gid >> 5;
    if (e >= E) return;
    int f = gid & 31;
    int s = src[e], d = dst[e];
    const float* hs = h + (size_t)s * (TF * FD) + f;
    float* aggd = agg + (size_t)d * (TF * FD) + f;
    #pragma unroll
    for (int t = 0; t < TF; ++t) {
        float we = w[(size_t)t * E + e];
        atomAddF(aggd + t * FD, we * hs[t * FD]);
    }
}

// out[row, o] = dot(agg[row, :], W[o, :]) + b[o]; fused sum/sumsq stats per o.
// stats layout: 32 slots x (32 sums + 32 sumsqs)
__global__ __launch_bounds__(256) void gemm_stats_kernel(
    const float* __restrict__ agg, const float* __restrict__ W,
    const float* __restrict__ bias, float* __restrict__ out,
    float* __restrict__ stats, int nrows)
{
    __shared__ float Wt[FD * FD];      // transposed: Wt[f*32 + o]
    __shared__ float rows[8 * FD];
    int tid = threadIdx.x;
    for (int i = tid; i < FD * FD; i += 256) {
        int o = i >> 5, f = i & 31;    // coalesced read of W (row-major o,f)
        Wt[f * FD + o] = W[i];
    }
    int o = tid & 31;
    int r = tid >> 5;                  // local row 0..7
    float b = bias[o];
    float sum = 0.f, sumsq = 0.f;
    int ngroups = (nrows + 7) >> 3;
    for (int g = blockIdx.x; g < ngroups; g += gridDim.x) {
        int row0 = g * 8;
        __syncthreads();               // Wt ready (1st iter) / rows reuse safe
        int idx = row0 * FD + tid;
        rows[tid] = (idx < nrows * FD) ? agg[idx] : 0.f;
        __syncthreads();
        int row = row0 + r;
        if (row < nrows) {
            float acc = b;
            #pragma unroll
            for (int f = 0; f < FD; ++f)
                acc = fmaf(rows[r * FD + f], Wt[f * FD + o], acc);
            out[(size_t)row * FD + o] = acc;
            sum += acc;
            sumsq += acc * acc;
        }
    }
    // block-reduce over r (same o), then one spread-slot atomic per (block,o)
    __syncthreads();
    rows[tid] = sum;
    Wt[tid] = sumsq;                   // reuse first 256 floats of Wt
    __syncthreads();
    for (int stride = 128; stride >= 32; stride >>= 1) {
        if (tid < stride) { rows[tid] += rows[tid + stride]; Wt[tid] += Wt[tid + stride]; }
        __syncthreads();
    }
    if (tid < 32) {
        int slot = blockIdx.x & 31;
        atomAddF(&stats[slot * 64 + tid], rows[tid]);
        atomAddF(&stats[slot * 64 + 32 + tid], Wt[tid]);
    }
}

__global__ void finalize_kernel(const float* __restrict__ stats,
                                const float* __restrict__ gamma,
                                const float* __restrict__ beta,
                                float* __restrict__ coef, float inv_count)
{
    int o = threadIdx.x;               // 32 threads
    float s = 0.f, sq = 0.f;
    #pragma unroll
    for (int k = 0; k < 32; ++k) { s += stats[k * 64 + o]; sq += stats[k * 64 + 32 + o]; }
    float mean = s * inv_count;
    float var  = sq * inv_count - mean * mean;
    float sc   = gamma[o] * rsqrtf(var + EPSV);
    coef[o]      = sc;
    coef[32 + o] = beta[o] - mean * sc;
}

__global__ __launch_bounds__(256) void norm_relu_kernel(
    float* __restrict__ x, const float* __restrict__ coef, int n4)
{
    int gid = blockIdx.x * 256 + threadIdx.x;
    if (gid >= n4) return;
    float4 v = ((const float4*)x)[gid];
    int o = (gid * 4) & 31;
    float4 r;
    r.x = fmaxf(0.f, fmaf(v.x, coef[o],     coef[32 + o]));
    r.y = fmaxf(0.f, fmaf(v.y, coef[o + 1], coef[33 + o]));
    r.z = fmaxf(0.f, fmaf(v.z, coef[o + 2], coef[34 + o]));
    r.w = fmaxf(0.f, fmaf(v.w, coef[o + 3], coef[35 + o]));
    ((float4*)x)[gid] = r;
}

extern "C" void kernel_launch(void* const* d_in, const int* in_sizes, int n_in,
                              void* d_out, int out_size, void* d_ws, size_t ws_size,
                              hipStream_t stream)
{
    const float* nf  = (const float*)d_in[0];
    const float* wgt = (const float*)d_in[1];
    const int*   src = (const int*)d_in[2];
    const int*   dst = (const int*)d_in[3];
    const float* Ws  = (const float*)d_in[4];
    const float* bs  = (const float*)d_in[5];
    const float* gam = (const float*)d_in[6];
    const float* bet = (const float*)d_in[7];

    int E  = in_sizes[2];
    int Nn = in_sizes[0] / FD;
    int nrows = Nn * TF;               // 80000

    float* out   = (float*)d_out;      // doubles as inter-layer h
    float* agg   = (float*)d_ws;                       // nrows*FD floats
    float* stats = agg + (size_t)nrows * FD;           // 32*64 floats
    float* coef  = stats + 32 * 64;                    // 64 floats

    int scatterBlocks = (E * 32 + 255) / 256;
    int n4 = nrows * FD / 4;
    float inv_count = 1.0f / (float)nrows;

    for (int l = 0; l < 3; ++l) {
        hipMemsetAsync(agg, 0, (size_t)nrows * FD * sizeof(float), stream);
        hipMemsetAsync(stats, 0, 32 * 64 * sizeof(float), stream);
        if (l == 0)
            scatter0_kernel<<<scatterBlocks, 256, 0, stream>>>(nf, wgt, src, dst, agg, E);
        else
            scatterL_kernel<<<scatterBlocks, 256, 0, stream>>>(out, wgt, src, dst, agg, E);
        gemm_stats_kernel<<<2048, 256, 0, stream>>>(
            agg, Ws + l * FD * FD, bs + l * FD, out, stats, nrows);
        finalize_kernel<<<1, 32, 0, stream>>>(
            stats, gam + l * FD, bet + l * FD, coef, inv_count);
        norm_relu_kernel<<<(n4 + 255) / 256, 256, 0, stream>>>(out, coef, n4);
    }
}

// Round 3
// 370.809 us; speedup vs baseline: 2.5019x; 2.5019x over previous
//
#include <hip/hip_runtime.h>

#define TF 8      // T (edge types)
#define FD 32     // F (features)
#define EPSV 1e-5f

__device__ __forceinline__ void atomAddF(float* p, float v) {
#if defined(__HIP_PLATFORM_AMD__)
    unsafeAtomicAdd(p, v);   // hardware global_atomic_add_f32
#else
    atomicAdd(p, v);
#endif
}

// ---------------------------------------------------------------- CSR build
__global__ __launch_bounds__(256) void hist_kernel(
    const int* __restrict__ dst, int* __restrict__ counts, int E)
{
    int e = blockIdx.x * 256 + threadIdx.x;
    if (e < E) atomicAdd(&counts[dst[e]], 1);
}

// single block, 1024 threads: exclusive scan of counts -> rowptr & cursor
__global__ __launch_bounds__(1024) void scan_kernel(
    const int* __restrict__ counts, int* __restrict__ rowptr,
    int* __restrict__ cursor, int Nn)
{
    __shared__ int totals[1024];
    int tid = threadIdx.x;
    int per = (Nn + 1023) >> 10;
    int start = tid * per;
    int end = min(start + per, Nn);
    if (end < start) end = start;
    int s = 0;
    for (int i = start; i < end; ++i) s += counts[i];
    totals[tid] = s;
    __syncthreads();
    for (int off = 1; off < 1024; off <<= 1) {
        int t2 = (tid >= off) ? totals[tid - off] : 0;
        __syncthreads();
        totals[tid] += t2;
        __syncthreads();
    }
    int running = totals[tid] - s;     // exclusive base for this chunk
    for (int i = start; i < end; ++i) {
        rowptr[i] = running;
        cursor[i] = running;
        running += counts[i];
    }
    if (tid == 1023) rowptr[Nn] = totals[1023];
}

// Path A fill: ssrc[j] = src of j-th dst-sorted edge; ws8[j*8+t] = w[t][e]
__global__ __launch_bounds__(256) void fillA_kernel(
    const int* __restrict__ src, const int* __restrict__ dst,
    const float* __restrict__ w, int* __restrict__ cursor,
    int* __restrict__ ssrc, float* __restrict__ ws8, int E)
{
    int e = blockIdx.x * 256 + threadIdx.x;
    if (e >= E) return;
    int d = dst[e];
    int j = atomicAdd(&cursor[d], 1);
    ssrc[j] = src[e];
    #pragma unroll
    for (int t = 0; t < TF; ++t)
        ws8[(size_t)j * TF + t] = w[(size_t)t * E + e];
}

// Path B fill: ssrc[j] = src, sedge[j] = original edge id
__global__ __launch_bounds__(256) void fillB_kernel(
    const int* __restrict__ src, const int* __restrict__ dst,
    int* __restrict__ cursor, int* __restrict__ ssrc,
    int* __restrict__ sedge, int E)
{
    int e = blockIdx.x * 256 + threadIdx.x;
    if (e >= E) return;
    int d = dst[e];
    int j = atomicAdd(&cursor[d], 1);
    ssrc[j] = src[e];
    sedge[j] = e;
}

// ------------------------------------------- fused aggregate + GEMM + stats
// one block per dst node; thread = (t, f). h (input) != out (output) buffer!
template <bool LAYER0, bool PACKED>
__global__ __launch_bounds__(256) void agg_gemm_kernel(
    const float* __restrict__ h, const int* __restrict__ rowptr,
    const int* __restrict__ ssrc, const int* __restrict__ sedge,
    const float* __restrict__ wsrc,   // PACKED ? ws8 : w (T,E)
    int E,
    const float* __restrict__ W, const float* __restrict__ bias,
    float* __restrict__ out, float* __restrict__ stats)
{
    __shared__ float Wt[FD * FD];      // Wt[f*32 + o]
    __shared__ float arow[TF * FD];
    __shared__ float qbuf[256];
    int tid = threadIdx.x;
    int t = tid >> 5, f = tid & 31;
    {   // stage W transposed (coalesced read of row-major (o,f))
        int ff = tid & 31;
        Wt[ff * FD + (tid >> 5)] = W[tid];
        Wt[ff * FD + ((tid + 256) >> 5)] = W[tid + 256];
        Wt[ff * FD + ((tid + 512) >> 5)] = W[tid + 512];
        Wt[ff * FD + ((tid + 768) >> 5)] = W[tid + 768];
    }
    int node = blockIdx.x;
    int rs = rowptr[node], re = rowptr[node + 1];

    float acc = 0.f;
    for (int j = rs; j < re; ++j) {
        int s = ssrc[j];               // uniform per block -> scalar load
        float wv;
        if (PACKED) wv = wsrc[(size_t)j * TF + t];
        else        wv = wsrc[(size_t)t * E + sedge[j]];
        float hv = LAYER0 ? h[(size_t)s * FD + f]
                          : h[(size_t)s * (TF * FD) + t * FD + f];
        acc = fmaf(wv, hv, acc);
    }
    arow[tid] = acc;
    __syncthreads();                   // orders Wt staging + arow

    float oval = bias[f];
    #pragma unroll
    for (int k = 0; k < FD; ++k)
        oval = fmaf(arow[t * FD + k], Wt[k * FD + f], oval);
    out[(size_t)node * (TF * FD) + tid] = oval;

    __syncthreads();                   // done reading arow/Wt
    arow[tid] = oval;                  // reuse as sum buffer
    qbuf[tid] = oval * oval;
    __syncthreads();
    #pragma unroll
    for (int stride = 128; stride >= 32; stride >>= 1) {
        if (tid < stride) {
            arow[tid] += arow[tid + stride];
            qbuf[tid] += qbuf[tid + stride];
        }
        __syncthreads();
    }
    if (tid < 32) {
        int slot = blockIdx.x & 31;
        atomAddF(&stats[slot * 64 + tid], arow[tid]);
        atomAddF(&stats[slot * 64 + 32 + tid], qbuf[tid]);
    }
}

__global__ void finalize_kernel(const float* __restrict__ stats,
                                const float* __restrict__ gamma,
                                const float* __restrict__ beta,
                                float* __restrict__ coef, float inv_count)
{
    int o = threadIdx.x;               // 32 threads
    float s = 0.f, sq = 0.f;
    #pragma unroll
    for (int k = 0; k < 32; ++k) { s += stats[k * 64 + o]; sq += stats[k * 64 + 32 + o]; }
    float mean = s * inv_count;
    float var  = sq * inv_count - mean * mean;
    float sc   = gamma[o] * rsqrtf(var + EPSV);
    coef[o]      = sc;
    coef[32 + o] = beta[o] - mean * sc;
}

__global__ __launch_bounds__(256) void norm_relu_kernel(
    float* __restrict__ x, const float* __restrict__ coef, int n4)
{
    int gid = blockIdx.x * 256 + threadIdx.x;
    if (gid >= n4) return;
    float4 v = ((const float4*)x)[gid];
    int o = (gid * 4) & 31;
    float4 r;
    r.x = fmaxf(0.f, fmaf(v.x, coef[o],     coef[32 + o]));
    r.y = fmaxf(0.f, fmaf(v.y, coef[o + 1], coef[33 + o]));
    r.z = fmaxf(0.f, fmaf(v.z, coef[o + 2], coef[34 + o]));
    r.w = fmaxf(0.f, fmaf(v.w, coef[o + 3], coef[35 + o]));
    ((float4*)x)[gid] = r;
}

// ------------------------------------------------ fallback (atomic scatter)
__global__ __launch_bounds__(256) void scatter0_kernel(
    const float* __restrict__ h, const float* __restrict__ w,
    const int* __restrict__ src, const int* __restrict__ dst,
    float* __restrict__ agg, int E)
{
    int gid = blockIdx.x * 256 + threadIdx.x;
    int e = gid >> 5;
    if (e >= E) return;
    int f = gid & 31;
    int s = src[e], d = dst[e];
    float hv = h[(size_t)s * FD + f];
    float* aggd = agg + (size_t)d * (TF * FD) + f;
    #pragma unroll
    for (int t = 0; t < TF; ++t)
        atomAddF(aggd + t * FD, w[(size_t)t * E + e] * hv);
}

__global__ __launch_bounds__(256) void scatterL_kernel(
    const float* __restrict__ h, const float* __restrict__ w,
    const int* __restrict__ src, const int* __restrict__ dst,
    float* __restrict__ agg, int E)
{
    int gid = blockIdx.x * 256 + threadIdx.x;
    int e = gid >> 5;
    if (e >= E) return;
    int f = gid & 31;
    int s = src[e], d = dst[e];
    const float* hs = h + (size_t)s * (TF * FD) + f;
    float* aggd = agg + (size_t)d * (TF * FD) + f;
    #pragma unroll
    for (int t = 0; t < TF; ++t)
        atomAddF(aggd + t * FD, w[(size_t)t * E + e] * hs[t * FD]);
}

__global__ __launch_bounds__(256) void gemm_stats_kernel(
    const float* __restrict__ agg, const float* __restrict__ W,
    const float* __restrict__ bias, float* __restrict__ out,
    float* __restrict__ stats, int nrows)
{
    __shared__ float Wt[FD * FD];
    __shared__ float rows[8 * FD];
    int tid = threadIdx.x;
    for (int i = tid; i < FD * FD; i += 256) {
        int o = i >> 5, f = i & 31;
        Wt[f * FD + o] = W[i];
    }
    int o = tid & 31;
    int r = tid >> 5;
    float b = bias[o];
    float sum = 0.f, sumsq = 0.f;
    int ngroups = (nrows + 7) >> 3;
    for (int g = blockIdx.x; g < ngroups; g += gridDim.x) {
        int row0 = g * 8;
        __syncthreads();
        int idx = row0 * FD + tid;
        rows[tid] = (idx < nrows * FD) ? agg[idx] : 0.f;
        __syncthreads();
        int row = row0 + r;
        if (row < nrows) {
            float acc = b;
            #pragma unroll
            for (int f2 = 0; f2 < FD; ++f2)
                acc = fmaf(rows[r * FD + f2], Wt[f2 * FD + o], acc);
            out[(size_t)row * FD + o] = acc;
            sum += acc;
            sumsq += acc * acc;
        }
    }
    __syncthreads();
    rows[tid] = sum;
    Wt[tid] = sumsq;
    __syncthreads();
    for (int stride = 128; stride >= 32; stride >>= 1) {
        if (tid < stride) { rows[tid] += rows[tid + stride]; Wt[tid] += Wt[tid + stride]; }
        __syncthreads();
    }
    if (tid < 32) {
        int slot = blockIdx.x & 31;
        atomAddF(&stats[slot * 64 + tid], rows[tid]);
        atomAddF(&stats[slot * 64 + 32 + tid], Wt[tid]);
    }
}

// ----------------------------------------------------------------- launch
extern "C" void kernel_launch(void* const* d_in, const int* in_sizes, int n_in,
                              void* d_out, int out_size, void* d_ws, size_t ws_size,
                              hipStream_t stream)
{
    const float* nf  = (const float*)d_in[0];
    const float* wgt = (const float*)d_in[1];
    const int*   src = (const int*)d_in[2];
    const int*   dst = (const int*)d_in[3];
    const float* Ws  = (const float*)d_in[4];
    const float* bs  = (const float*)d_in[5];
    const float* gam = (const float*)d_in[6];
    const float* bet = (const float*)d_in[7];

    int E  = in_sizes[2];
    int Nn = in_sizes[0] / FD;
    int nrows = Nn * TF;
    int n4 = nrows * FD / 4;
    float inv_count = 1.0f / (float)nrows;
    float* out = (float*)d_out;

    size_t idxInts = (size_t)(3 * Nn + 4);                 // counts,cursor,rowptr(+pad)
    size_t hbufF   = (size_t)nrows * FD;                   // ping-pong h buffer
    size_t needA = (idxInts + (size_t)E + (size_t)E * TF + hbufF + 2048 + 64) * 4;
    size_t needB = (idxInts + 2 * (size_t)E + hbufF + 2048 + 64) * 4;

    int eb = (E + 255) / 256;

    if (ws_size >= needB) {
        bool packed = (ws_size >= needA);
        int*   counts = (int*)d_ws;
        int*   cursor = counts + Nn;
        int*   rowptr = cursor + Nn;
        int*   ssrc   = counts + idxInts;          // 16B-aligned (30004*4)
        int*   sedge  = ssrc + E;                  // Path B only
        float* ws8    = (float*)(ssrc + E);        // Path A only (same slot)
        float* tailF  = packed ? (ws8 + (size_t)E * TF) : (float*)(sedge + E);
        float* hbuf   = tailF;
        float* stats  = hbuf + hbufF;
        float* coef   = stats + 2048;

        hipMemsetAsync(counts, 0, (size_t)Nn * sizeof(int), stream);
        hist_kernel<<<eb, 256, 0, stream>>>(dst, counts, E);
        scan_kernel<<<1, 1024, 0, stream>>>(counts, rowptr, cursor, Nn);
        if (packed)
            fillA_kernel<<<eb, 256, 0, stream>>>(src, dst, wgt, cursor, ssrc, ws8, E);
        else
            fillB_kernel<<<eb, 256, 0, stream>>>(src, dst, cursor, ssrc, sedge, E);

        // ping-pong: L0 nf->out, L1 out->hbuf, L2 hbuf->out  (in != out always)
        const float* lin[3] = { nf, out, hbuf };
        float*       lout[3] = { out, hbuf, out };

        for (int l = 0; l < 3; ++l) {
            hipMemsetAsync(stats, 0, 2048 * sizeof(float), stream);
            const float* wp = packed ? ws8 : wgt;
            if (l == 0) {
                if (packed)
                    agg_gemm_kernel<true, true><<<Nn, 256, 0, stream>>>(
                        lin[l], rowptr, ssrc, sedge, wp, E, Ws, bs, lout[l], stats);
                else
                    agg_gemm_kernel<true, false><<<Nn, 256, 0, stream>>>(
                        lin[l], rowptr, ssrc, sedge, wp, E, Ws, bs, lout[l], stats);
            } else {
                if (packed)
                    agg_gemm_kernel<false, true><<<Nn, 256, 0, stream>>>(
                        lin[l], rowptr, ssrc, sedge, wp, E,
                        Ws + l * FD * FD, bs + l * FD, lout[l], stats);
                else
                    agg_gemm_kernel<false, false><<<Nn, 256, 0, stream>>>(
                        lin[l], rowptr, ssrc, sedge, wp, E,
                        Ws + l * FD * FD, bs + l * FD, lout[l], stats);
            }
            finalize_kernel<<<1, 32, 0, stream>>>(
                stats, gam + l * FD, bet + l * FD, coef, inv_count);
            norm_relu_kernel<<<(n4 + 255) / 256, 256, 0, stream>>>(lout[l], coef, n4);
        }
    } else {
        // fallback: round-0 atomic scatter path (proven)
        float* agg   = (float*)d_ws;
        float* stats = agg + (size_t)nrows * FD;
        float* coef  = stats + 2048;
        int scatterBlocks = (E * 32 + 255) / 256;
        for (int l = 0; l < 3; ++l) {
            hipMemsetAsync(agg, 0, (size_t)nrows * FD * sizeof(float), stream);
            hipMemsetAsync(stats, 0, 2048 * sizeof(float), stream);
            if (l == 0)
                scatter0_kernel<<<scatterBlocks, 256, 0, stream>>>(nf, wgt, src, dst, agg, E);
            else
                scatterL_kernel<<<scatterBlocks, 256, 0, stream>>>(out, wgt, src, dst, agg, E);
            gemm_stats_kernel<<<2048, 256, 0, stream>>>(
                agg, Ws + l * FD * FD, bs + l * FD, out, stats, nrows);
            finalize_kernel<<<1, 32, 0, stream>>>(
                stats, gam + l * FD, bet + l * FD, coef, inv_count);
            norm_relu_kernel<<<(n4 + 255) / 256, 256, 0, stream>>>(out, coef, n4);
        }
    }
}

// Round 5
// 261.656 us; speedup vs baseline: 3.5456x; 1.4172x over previous
//
#include <hip/hip_runtime.h>

#define TF 8      // T (edge types)
#define FD 32     // F (features)
#define EPSV 1e-5f

__device__ __forceinline__ void atomAddF(float* p, float v) {
#if defined(__HIP_PLATFORM_AMD__)
    unsafeAtomicAdd(p, v);
#else
    atomicAdd(p, v);
#endif
}

// ---------------------------------------------------------------- CSR build
__global__ __launch_bounds__(256) void hist_kernel(
    const int* __restrict__ dst, int* __restrict__ counts, int E)
{
    int e = blockIdx.x * 256 + threadIdx.x;
    if (e < E) atomicAdd(&counts[dst[e]], 1);
}

__global__ __launch_bounds__(1024) void scan_kernel(
    const int* __restrict__ counts, int* __restrict__ rowptr,
    int* __restrict__ cursor, int Nn)
{
    __shared__ int totals[1024];
    int tid = threadIdx.x;
    int per = (Nn + 1023) >> 10;
    int start = tid * per;
    int end = min(start + per, Nn);
    if (end < start) end = start;
    int s = 0;
    for (int i = start; i < end; ++i) s += counts[i];
    totals[tid] = s;
    __syncthreads();
    for (int off = 1; off < 1024; off <<= 1) {
        int t2 = (tid >= off) ? totals[tid - off] : 0;
        __syncthreads();
        totals[tid] += t2;
        __syncthreads();
    }
    int running = totals[tid] - s;
    for (int i = start; i < end; ++i) {
        rowptr[i] = running;
        cursor[i] = running;
        running += counts[i];
    }
    if (tid == 1023) rowptr[Nn] = totals[1023];
}

// ssrc[j] = src of j-th dst-sorted edge; ws8[j*8+t] = w[t][e]
__global__ __launch_bounds__(256) void fillA_kernel(
    const int* __restrict__ src, const int* __restrict__ dst,
    const float* __restrict__ w, int* __restrict__ cursor,
    int* __restrict__ ssrc, float* __restrict__ ws8, int E)
{
    int e = blockIdx.x * 256 + threadIdx.x;
    if (e >= E) return;
    int d = dst[e];
    int j = atomicAdd(&cursor[d], 1);
    ssrc[j] = src[e];
    #pragma unroll
    for (int t = 0; t < TF; ++t)
        ws8[(size_t)j * TF + t] = w[(size_t)t * E + e];
}

// ---------------- fused [norm+relu of prev layer] + aggregate + GEMM + stats
// 8 edge slots per block: thread = (slot, f); acc[t] in registers.
// MODE 0: h is (N,F) raw input.  MODE 1: h is (N,T,F) RAW; apply
// relu(h*cA[f]+cB[f]) on the fly (coefIn from previous finalize).
template <int MODE>
__global__ __launch_bounds__(256) void agg_gemm2_kernel(
    const float* __restrict__ h, const float* __restrict__ coefIn,
    const int* __restrict__ rowptr, const int* __restrict__ ssrc,
    const float* __restrict__ ws8,
    const float* __restrict__ W, const float* __restrict__ bias,
    float* __restrict__ out, float* __restrict__ stats)
{
    __shared__ float Wt[FD * FD];          // Wt[k*32 + o]
    __shared__ float red[8 * TF * FD];     // [slot][t][f], reused later
    int tid = threadIdx.x;
    int slot = tid >> 5, f = tid & 31;
    {   // stage W transposed (coalesced read of row-major (o,f))
        int ff = tid & 31;
        Wt[ff * FD + (tid >> 5)] = W[tid];
        Wt[ff * FD + ((tid + 256) >> 5)] = W[tid + 256];
        Wt[ff * FD + ((tid + 512) >> 5)] = W[tid + 512];
        Wt[ff * FD + ((tid + 768) >> 5)] = W[tid + 768];
    }
    float cA = 0.f, cB = 0.f;
    if (MODE == 1) { cA = coefIn[f]; cB = coefIn[FD + f]; }

    int node = blockIdx.x;
    int rs = rowptr[node], re = rowptr[node + 1];

    float acc[TF];
    #pragma unroll
    for (int t = 0; t < TF; ++t) acc[t] = 0.f;

    int j = rs + slot;
    int s = (j < re) ? ssrc[j] : 0;
    for (; j < re; j += 8) {
        int jn = j + 8;
        int s_next = (jn < re) ? ssrc[jn] : 0;
        float4 wA = *(const float4*)(ws8 + (size_t)j * TF);
        float4 wB = *(const float4*)(ws8 + (size_t)j * TF + 4);
        if (MODE == 0) {
            float hv = h[(size_t)s * FD + f];
            acc[0] = fmaf(wA.x, hv, acc[0]);
            acc[1] = fmaf(wA.y, hv, acc[1]);
            acc[2] = fmaf(wA.z, hv, acc[2]);
            acc[3] = fmaf(wA.w, hv, acc[3]);
            acc[4] = fmaf(wB.x, hv, acc[4]);
            acc[5] = fmaf(wB.y, hv, acc[5]);
            acc[6] = fmaf(wB.z, hv, acc[6]);
            acc[7] = fmaf(wB.w, hv, acc[7]);
        } else {
            const float* hp = h + (size_t)s * (TF * FD) + f;
            float hv[TF];
            #pragma unroll
            for (int t = 0; t < TF; ++t) hv[t] = hp[t * FD];
            #pragma unroll
            for (int t = 0; t < TF; ++t) {
                float hn = fmaxf(0.f, fmaf(hv[t], cA, cB));
                float wv = (t == 0) ? wA.x : (t == 1) ? wA.y : (t == 2) ? wA.z :
                           (t == 3) ? wA.w : (t == 4) ? wB.x : (t == 5) ? wB.y :
                           (t == 6) ? wB.z : wB.w;
                acc[t] = fmaf(wv, hn, acc[t]);
            }
        }
        s = s_next;
    }
    // cross-slot reduction: red[slot][t][f]
    #pragma unroll
    for (int t = 0; t < TF; ++t)
        red[slot * (TF * FD) + t * FD + f] = acc[t];
    __syncthreads();
    int t2 = tid >> 5;                      // reinterpret thread as (t, f)
    float asum = 0.f;
    #pragma unroll
    for (int sl = 0; sl < 8; ++sl)
        asum += red[sl * (TF * FD) + t2 * FD + f];
    __syncthreads();                        // all reads of red done
    red[t2 * FD + f] = asum;                // arow in first 256 words
    __syncthreads();

    float oval = bias[f];
    #pragma unroll
    for (int k = 0; k < FD; ++k)
        oval = fmaf(red[t2 * FD + k], Wt[k * FD + f], oval);
    out[(size_t)node * (TF * FD) + tid] = oval;   // RAW (un-normed) output

    __syncthreads();                        // done reading red/Wt
    red[tid] = oval;
    red[256 + tid] = oval * oval;
    __syncthreads();
    #pragma unroll
    for (int stride = 128; stride >= 32; stride >>= 1) {
        if (tid < stride) {
            red[tid] += red[tid + stride];
            red[256 + tid] += red[256 + tid + stride];
        }
        __syncthreads();
    }
    if (tid < 32) {
        int slot2 = blockIdx.x & 31;
        atomAddF(&stats[slot2 * 64 + tid], red[tid]);
        atomAddF(&stats[slot2 * 64 + 32 + tid], red[256 + tid]);
    }
}

__global__ void finalize_kernel(const float* __restrict__ stats,
                                const float* __restrict__ gamma,
                                const float* __restrict__ beta,
                                float* __restrict__ coef, float inv_count)
{
    int o = threadIdx.x;               // 32 threads
    float s = 0.f, sq = 0.f;
    #pragma unroll
    for (int k = 0; k < 32; ++k) { s += stats[k * 64 + o]; sq += stats[k * 64 + 32 + o]; }
    float mean = s * inv_count;
    float var  = sq * inv_count - mean * mean;
    float sc   = gamma[o] * rsqrtf(var + EPSV);
    coef[o]      = sc;
    coef[FD + o] = beta[o] - mean * sc;
}

__global__ __launch_bounds__(256) void norm_relu_kernel(
    float* __restrict__ x, const float* __restrict__ coef, int n4)
{
    int gid = blockIdx.x * 256 + threadIdx.x;
    if (gid >= n4) return;
    float4 v = ((const float4*)x)[gid];
    int o = (gid * 4) & 31;
    float4 r;
    r.x = fmaxf(0.f, fmaf(v.x, coef[o],     coef[32 + o]));
    r.y = fmaxf(0.f, fmaf(v.y, coef[o + 1], coef[33 + o]));
    r.z = fmaxf(0.f, fmaf(v.z, coef[o + 2], coef[34 + o]));
    r.w = fmaxf(0.f, fmaf(v.w, coef[o + 3], coef[35 + o]));
    ((float4*)x)[gid] = r;
}

// ------------------------------------------------ fallback (atomic scatter)
__global__ __launch_bounds__(256) void scatter0_kernel(
    const float* __restrict__ h, const float* __restrict__ w,
    const int* __restrict__ src, const int* __restrict__ dst,
    float* __restrict__ agg, int E)
{
    int gid = blockIdx.x * 256 + threadIdx.x;
    int e = gid >> 5;
    if (e >= E) return;
    int f = gid & 31;
    int s = src[e], d = dst[e];
    float hv = h[(size_t)s * FD + f];
    float* aggd = agg + (size_t)d * (TF * FD) + f;
    #pragma unroll
    for (int t = 0; t < TF; ++t)
        atomAddF(aggd + t * FD, w[(size_t)t * E + e] * hv);
}

__global__ __launch_bounds__(256) void scatterL_kernel(
    const float* __restrict__ h, const float* __restrict__ w,
    const int* __restrict__ src, const int* __restrict__ dst,
    float* __restrict__ agg, int E)
{
    int gid = blockIdx.x * 256 + threadIdx.x;
    int e = gid >> 5;
    if (e >= E) return;
    int f = gid & 31;
    int s = src[e], d = dst[e];
    const float* hs = h + (size_t)s * (TF * FD) + f;
    float* aggd = agg + (size_t)d * (TF * FD) + f;
    #pragma unroll
    for (int t = 0; t < TF; ++t)
        atomAddF(aggd + t * FD, w[(size_t)t * E + e] * hs[t * FD]);
}

__global__ __launch_bounds__(256) void gemm_stats_kernel(
    const float* __restrict__ agg, const float* __restrict__ W,
    const float* __restrict__ bias, float* __restrict__ out,
    float* __restrict__ stats, int nrows)
{
    __shared__ float Wt[FD * FD];
    __shared__ float rows[8 * FD];
    int tid = threadIdx.x;
    for (int i = tid; i < FD * FD; i += 256) {
        int o = i >> 5, f = i & 31;
        Wt[f * FD + o] = W[i];
    }
    int o = tid & 31;
    int r = tid >> 5;
    float b = bias[o];
    float sum = 0.f, sumsq = 0.f;
    int ngroups = (nrows + 7) >> 3;
    for (int g = blockIdx.x; g < ngroups; g += gridDim.x) {
        int row0 = g * 8;
        __syncthreads();
        int idx = row0 * FD + tid;
        rows[tid] = (idx < nrows * FD) ? agg[idx] : 0.f;
        __syncthreads();
        int row = row0 + r;
        if (row < nrows) {
            float acc = b;
            #pragma unroll
            for (int f2 = 0; f2 < FD; ++f2)
                acc = fmaf(rows[r * FD + f2], Wt[f2 * FD + o], acc);
            out[(size_t)row * FD + o] = acc;
            sum += acc;
            sumsq += acc * acc;
        }
    }
    __syncthreads();
    rows[tid] = sum;
    Wt[tid] = sumsq;
    __syncthreads();
    for (int stride = 128; stride >= 32; stride >>= 1) {
        if (tid < stride) { rows[tid] += rows[tid + stride]; Wt[tid] += Wt[tid + stride]; }
        __syncthreads();
    }
    if (tid < 32) {
        int slot = blockIdx.x & 31;
        atomAddF(&stats[slot * 64 + tid], rows[tid]);
        atomAddF(&stats[slot * 64 + 32 + tid], Wt[tid]);
    }
}

// ----------------------------------------------------------------- launch
extern "C" void kernel_launch(void* const* d_in, const int* in_sizes, int n_in,
                              void* d_out, int out_size, void* d_ws, size_t ws_size,
                              hipStream_t stream)
{
    const float* nf  = (const float*)d_in[0];
    const float* wgt = (const float*)d_in[1];
    const int*   src = (const int*)d_in[2];
    const int*   dst = (const int*)d_in[3];
    const float* Ws  = (const float*)d_in[4];
    const float* bs  = (const float*)d_in[5];
    const float* gam = (const float*)d_in[6];
    const float* bet = (const float*)d_in[7];

    int E  = in_sizes[2];
    int Nn = in_sizes[0] / FD;
    int nrows = Nn * TF;
    int n4 = nrows * FD / 4;
    float inv_count = 1.0f / (float)nrows;
    float* out = (float*)d_out;

    size_t idxInts = (size_t)(3 * Nn + 4);
    size_t hbufF   = (size_t)nrows * FD;
    // same layout/size as round-3 Path A (proven to fit): idx + ssrc + ws8 + hbuf + stats(3*2048) + coef(3*64)
    size_t needA = (idxInts + (size_t)E + (size_t)E * TF + hbufF + 3 * 2048 + 3 * 64) * 4;

    int eb = (E + 255) / 256;

    if (ws_size >= needA) {
        int*   counts = (int*)d_ws;
        int*   cursor = counts + Nn;
        int*   rowptr = cursor + Nn;
        int*   ssrc   = counts + idxInts;
        float* ws8    = (float*)(ssrc + E);
        float* hbuf   = ws8 + (size_t)E * TF;
        float* stats  = hbuf + hbufF;             // 3 layers x 2048
        float* coef   = stats + 3 * 2048;         // 3 layers x 64

        hipMemsetAsync(counts, 0, (size_t)Nn * sizeof(int), stream);
        hipMemsetAsync(stats, 0, 3 * 2048 * sizeof(float), stream);
        hist_kernel<<<eb, 256, 0, stream>>>(dst, counts, E);
        scan_kernel<<<1, 1024, 0, stream>>>(counts, rowptr, cursor, Nn);
        fillA_kernel<<<eb, 256, 0, stream>>>(src, dst, wgt, cursor, ssrc, ws8, E);

        // L0: nf -> d_out (raw);  L1: d_out -> hbuf (raw, norm0 on the fly);
        // L2: hbuf -> d_out (raw, norm1 on the fly); final norm2 in-place.
        agg_gemm2_kernel<0><<<Nn, 256, 0, stream>>>(
            nf, nullptr, rowptr, ssrc, ws8, Ws, bs, out, stats);
        finalize_kernel<<<1, 32, 0, stream>>>(
            stats, gam, bet, coef, inv_count);
        agg_gemm2_kernel<1><<<Nn, 256, 0, stream>>>(
            out, coef, rowptr, ssrc, ws8, Ws + FD * FD, bs + FD,
            hbuf, stats + 2048);
        finalize_kernel<<<1, 32, 0, stream>>>(
            stats + 2048, gam + FD, bet + FD, coef + 64, inv_count);
        agg_gemm2_kernel<1><<<Nn, 256, 0, stream>>>(
            hbuf, coef + 64, rowptr, ssrc, ws8, Ws + 2 * FD * FD, bs + 2 * FD,
            out, stats + 2 * 2048);
        finalize_kernel<<<1, 32, 0, stream>>>(
            stats + 2 * 2048, gam + 2 * FD, bet + 2 * FD, coef + 2 * 64, inv_count);
        norm_relu_kernel<<<(n4 + 255) / 256, 256, 0, stream>>>(out, coef + 2 * 64, n4);
    } else {
        // fallback: round-0 atomic scatter path (proven)
        float* agg   = (float*)d_ws;
        float* stats = agg + (size_t)nrows * FD;
        float* coef  = stats + 2048;
        int scatterBlocks = (E * 32 + 255) / 256;
        for (int l = 0; l < 3; ++l) {
            hipMemsetAsync(agg, 0, (size_t)nrows * FD * sizeof(float), stream);
            hipMemsetAsync(stats, 0, 2048 * sizeof(float), stream);
            if (l == 0)
                scatter0_kernel<<<scatterBlocks, 256, 0, stream>>>(nf, wgt, src, dst, agg, E);
            else
                scatterL_kernel<<<scatterBlocks, 256, 0, stream>>>(out, wgt, src, dst, agg, E);
            gemm_stats_kernel<<<2048, 256, 0, stream>>>(
                agg, Ws + l * FD * FD, bs + l * FD, out, stats, nrows);
            finalize_kernel<<<1, 32, 0, stream>>>(
                stats, gam + l * FD, bet + l * FD, coef, inv_count);
            norm_relu_kernel<<<(n4 + 255) / 256, 256, 0, stream>>>(out, coef, n4);
        }
    }
}

// Round 6
// 251.205 us; speedup vs baseline: 3.6931x; 1.0416x over previous
//
#include <hip/hip_runtime.h>

#define TF 8      // T (edge types)
#define FD 32     // F (features)
#define EPSV 1e-5f

__device__ __forceinline__ void atomAddF(float* p, float v) {
#if defined(__HIP_PLATFORM_AMD__)
    unsafeAtomicAdd(p, v);
#else
    atomicAdd(p, v);
#endif
}

// f32 -> bf16 (RNE) in low 16 bits
__device__ __forceinline__ unsigned int f2bfu(float x) {
    unsigned int u = __float_as_uint(x);
    return (u + 0x7FFFu + ((u >> 16) & 1u)) >> 16;
}
// bf16 from uint word: half 0 = low 16, half 1 = high 16
__device__ __forceinline__ float bfx(unsigned int w, int hi) {
    return __uint_as_float(hi ? (w & 0xFFFF0000u) : (w << 16));
}

// ---------------------------------------------------------------- CSR build
__global__ __launch_bounds__(256) void hist_kernel(
    const int* __restrict__ dst, int* __restrict__ counts, int E)
{
    int e = blockIdx.x * 256 + threadIdx.x;
    if (e < E) atomicAdd(&counts[dst[e]], 1);
}

__global__ __launch_bounds__(1024) void scan_kernel(
    const int* __restrict__ counts, int* __restrict__ rowptr,
    int* __restrict__ cursor, int Nn)
{
    __shared__ int totals[1024];
    int tid = threadIdx.x;
    int per = (Nn + 1023) >> 10;
    int start = tid * per;
    int end = min(start + per, Nn);
    if (end < start) end = start;
    int s = 0;
    for (int i = start; i < end; ++i) s += counts[i];
    totals[tid] = s;
    __syncthreads();
    for (int off = 1; off < 1024; off <<= 1) {
        int t2 = (tid >= off) ? totals[tid - off] : 0;
        __syncthreads();
        totals[tid] += t2;
        __syncthreads();
    }
    int running = totals[tid] - s;
    for (int i = start; i < end; ++i) {
        rowptr[i] = running;
        cursor[i] = running;
        running += counts[i];
    }
    if (tid == 1023) rowptr[Nn] = totals[1023];
}

// ssrc[j] = src of j-th dst-sorted edge; wsb[j] = 8 bf16 weights (t0..t7)
__global__ __launch_bounds__(256) void fillA_kernel(
    const int* __restrict__ src, const int* __restrict__ dst,
    const float* __restrict__ w, int* __restrict__ cursor,
    int* __restrict__ ssrc, uint4* __restrict__ wsb, int E)
{
    int e = blockIdx.x * 256 + threadIdx.x;
    if (e >= E) return;
    int d = dst[e];
    int j = atomicAdd(&cursor[d], 1);
    ssrc[j] = src[e];
    uint4 p;
    p.x = f2bfu(w[(size_t)0 * E + e]) | (f2bfu(w[(size_t)1 * E + e]) << 16);
    p.y = f2bfu(w[(size_t)2 * E + e]) | (f2bfu(w[(size_t)3 * E + e]) << 16);
    p.z = f2bfu(w[(size_t)4 * E + e]) | (f2bfu(w[(size_t)5 * E + e]) << 16);
    p.w = f2bfu(w[(size_t)6 * E + e]) | (f2bfu(w[(size_t)7 * E + e]) << 16);
    wsb[j] = p;
}

// ---------------- fused [norm+relu of prev layer] + aggregate + GEMM + stats
// 8 edge slots per block: thread = (slot, f); acc[t] in registers.
// MODE 0: hf is (N,F) f32 input, broadcast over t.
// MODE 1: hb is bf16 packed (N, F, 4 uints), raw; apply relu(x*cA[f]+cB[f]).
// OUTB 1: write bf16 packed raw to outU;  OUTB 0: write f32 (N,T,F) to outF.
template <int MODE, int OUTB>
__global__ __launch_bounds__(256) void agg_gemm3_kernel(
    const float* __restrict__ hf, const uint4* __restrict__ hb,
    const float* __restrict__ coefIn,
    const int* __restrict__ rowptr, const int* __restrict__ ssrc,
    const uint4* __restrict__ wsb,
    const float* __restrict__ W, const float* __restrict__ bias,
    unsigned int* __restrict__ outU, float* __restrict__ outF,
    float* __restrict__ stats)
{
    __shared__ float Wt[FD * FD];          // Wt[k*32 + o]
    __shared__ float red[512];             // stats/arow staging
    __shared__ float pacc[8 * TF * FD];    // [slot][t][f]
    int tid = threadIdx.x;
    int slot = tid >> 5, f = tid & 31;
    {   // stage W transposed (coalesced read of row-major (o,f))
        int ff = tid & 31;
        Wt[ff * FD + (tid >> 5)] = W[tid];
        Wt[ff * FD + ((tid + 256) >> 5)] = W[tid + 256];
        Wt[ff * FD + ((tid + 512) >> 5)] = W[tid + 512];
        Wt[ff * FD + ((tid + 768) >> 5)] = W[tid + 768];
    }
    float cA = 0.f, cB = 0.f;
    if (MODE == 1) { cA = coefIn[f]; cB = coefIn[FD + f]; }

    int node = blockIdx.x;
    int rs = rowptr[node], re = rowptr[node + 1];

    float acc[TF];
    #pragma unroll
    for (int t = 0; t < TF; ++t) acc[t] = 0.f;

    int j = rs + slot;
    int s = (j < re) ? ssrc[j] : 0;
    for (; j < re; j += 8) {
        int jn = j + 8;
        int s_next = (jn < re) ? ssrc[jn] : 0;
        uint4 wp = wsb[j];
        unsigned int ww[4] = { wp.x, wp.y, wp.z, wp.w };
        if (MODE == 0) {
            float hv = hf[(size_t)s * FD + f];
            #pragma unroll
            for (int t = 0; t < TF; ++t)
                acc[t] = fmaf(bfx(ww[t >> 1], t & 1), hv, acc[t]);
        } else {
            uint4 hp = hb[(size_t)s * FD + f];
            unsigned int hw[4] = { hp.x, hp.y, hp.z, hp.w };
            #pragma unroll
            for (int t = 0; t < TF; ++t) {
                float hr = bfx(hw[t >> 1], t & 1);
                float hn = fmaxf(0.f, fmaf(hr, cA, cB));
                acc[t] = fmaf(bfx(ww[t >> 1], t & 1), hn, acc[t]);
            }
        }
        s = s_next;
    }
    // cross-slot reduction: pacc[slot][t][f]
    #pragma unroll
    for (int t = 0; t < TF; ++t)
        pacc[slot * (TF * FD) + t * FD + f] = acc[t];
    __syncthreads();
    int t2 = tid >> 5;                      // reinterpret thread as (t, f)
    float asum = 0.f;
    #pragma unroll
    for (int sl = 0; sl < 8; ++sl)
        asum += pacc[sl * (TF * FD) + t2 * FD + f];
    red[tid] = asum;                        // arow[t][f] in red[0..255]
    __syncthreads();

    float oval = bias[f];
    #pragma unroll
    for (int k = 0; k < FD; ++k)
        oval = fmaf(red[t2 * FD + k], Wt[k * FD + f], oval);
    if (!OUTB)
        outF[(size_t)node * (TF * FD) + tid] = oval;   // RAW f32 output

    __syncthreads();                        // done reading red/Wt
    red[tid] = oval;                        // by (t,f): red[t*32+f]
    red[256 + tid] = oval * oval;
    __syncthreads();
    if (OUTB) {
        // pack bf16: uint q of node row f holds t=2q (lo), t=2q+1 (hi)
        if (tid < 128) {
            int ff = tid >> 2, q = tid & 3;
            unsigned int lo = f2bfu(red[(q * 2) * FD + ff]);
            unsigned int hi = f2bfu(red[(q * 2 + 1) * FD + ff]);
            outU[(size_t)node * 128 + ff * 4 + q] = lo | (hi << 16);
        }
        __syncthreads();                    // repack reads before tree writes
    }
    #pragma unroll
    for (int stride = 128; stride >= 32; stride >>= 1) {
        if (tid < stride) {
            red[tid] += red[tid + stride];
            red[256 + tid] += red[256 + tid + stride];
        }
        __syncthreads();
    }
    if (tid < 32) {
        int slot2 = blockIdx.x & 31;
        atomAddF(&stats[slot2 * 64 + tid], red[tid]);
        atomAddF(&stats[slot2 * 64 + 32 + tid], red[256 + tid]);
    }
}

__global__ void finalize_kernel(const float* __restrict__ stats,
                                const float* __restrict__ gamma,
                                const float* __restrict__ beta,
                                float* __restrict__ coef, float inv_count)
{
    int o = threadIdx.x;               // 32 threads
    float s = 0.f, sq = 0.f;
    #pragma unroll
    for (int k = 0; k < 32; ++k) { s += stats[k * 64 + o]; sq += stats[k * 64 + 32 + o]; }
    float mean = s * inv_count;
    float var  = sq * inv_count - mean * mean;
    float sc   = gamma[o] * rsqrtf(var + EPSV);
    coef[o]      = sc;
    coef[FD + o] = beta[o] - mean * sc;
}

__global__ __launch_bounds__(256) void norm_relu_kernel(
    float* __restrict__ x, const float* __restrict__ coef, int n4)
{
    int gid = blockIdx.x * 256 + threadIdx.x;
    if (gid >= n4) return;
    float4 v = ((const float4*)x)[gid];
    int o = (gid * 4) & 31;
    float4 r;
    r.x = fmaxf(0.f, fmaf(v.x, coef[o],     coef[32 + o]));
    r.y = fmaxf(0.f, fmaf(v.y, coef[o + 1], coef[33 + o]));
    r.z = fmaxf(0.f, fmaf(v.z, coef[o + 2], coef[34 + o]));
    r.w = fmaxf(0.f, fmaf(v.w, coef[o + 3], coef[35 + o]));
    ((float4*)x)[gid] = r;
}

// ------------------------------------------------ fallback (atomic scatter)
__global__ __launch_bounds__(256) void scatter0_kernel(
    const float* __restrict__ h, const float* __restrict__ w,
    const int* __restrict__ src, const int* __restrict__ dst,
    float* __restrict__ agg, int E)
{
    int gid = blockIdx.x * 256 + threadIdx.x;
    int e = gid >> 5;
    if (e >= E) return;
    int f = gid & 31;
    int s = src[e], d = dst[e];
    float hv = h[(size_t)s * FD + f];
    float* aggd = agg + (size_t)d * (TF * FD) + f;
    #pragma unroll
    for (int t = 0; t < TF; ++t)
        atomAddF(aggd + t * FD, w[(size_t)t * E + e] * hv);
}

__global__ __launch_bounds__(256) void scatterL_kernel(
    const float* __restrict__ h, const float* __restrict__ w,
    const int* __restrict__ src, const int* __restrict__ dst,
    float* __restrict__ agg, int E)
{
    int gid = blockIdx.x * 256 + threadIdx.x;
    int e = gid >> 5;
    if (e >= E) return;
    int f = gid & 31;
    int s = src[e], d = dst[e];
    const float* hs = h + (size_t)s * (TF * FD) + f;
    float* aggd = agg + (size_t)d * (TF * FD) + f;
    #pragma unroll
    for (int t = 0; t < TF; ++t)
        atomAddF(aggd + t * FD, w[(size_t)t * E + e] * hs[t * FD]);
}

__global__ __launch_bounds__(256) void gemm_stats_kernel(
    const float* __restrict__ agg, const float* __restrict__ W,
    const float* __restrict__ bias, float* __restrict__ out,
    float* __restrict__ stats, int nrows)
{
    __shared__ float Wt[FD * FD];
    __shared__ float rows[8 * FD];
    int tid = threadIdx.x;
    for (int i = tid; i < FD * FD; i += 256) {
        int o = i >> 5, f = i & 31;
        Wt[f * FD + o] = W[i];
    }
    int o = tid & 31;
    int r = tid >> 5;
    float b = bias[o];
    float sum = 0.f, sumsq = 0.f;
    int ngroups = (nrows + 7) >> 3;
    for (int g = blockIdx.x; g < ngroups; g += gridDim.x) {
        int row0 = g * 8;
        __syncthreads();
        int idx = row0 * FD + tid;
        rows[tid] = (idx < nrows * FD) ? agg[idx] : 0.f;
        __syncthreads();
        int row = row0 + r;
        if (row < nrows) {
            float acc = b;
            #pragma unroll
            for (int f2 = 0; f2 < FD; ++f2)
                acc = fmaf(rows[r * FD + f2], Wt[f2 * FD + o], acc);
            out[(size_t)row * FD + o] = acc;
            sum += acc;
            sumsq += acc * acc;
        }
    }
    __syncthreads();
    rows[tid] = sum;
    Wt[tid] = sumsq;
    __syncthreads();
    for (int stride = 128; stride >= 32; stride >>= 1) {
        if (tid < stride) { rows[tid] += rows[tid + stride]; Wt[tid] += Wt[tid + stride]; }
        __syncthreads();
    }
    if (tid < 32) {
        int slot = blockIdx.x & 31;
        atomAddF(&stats[slot * 64 + tid], rows[tid]);
        atomAddF(&stats[slot * 64 + 32 + tid], Wt[tid]);
    }
}

// ----------------------------------------------------------------- launch
extern "C" void kernel_launch(void* const* d_in, const int* in_sizes, int n_in,
                              void* d_out, int out_size, void* d_ws, size_t ws_size,
                              hipStream_t stream)
{
    const float* nf  = (const float*)d_in[0];
    const float* wgt = (const float*)d_in[1];
    const int*   src = (const int*)d_in[2];
    const int*   dst = (const int*)d_in[3];
    const float* Ws  = (const float*)d_in[4];
    const float* bs  = (const float*)d_in[5];
    const float* gam = (const float*)d_in[6];
    const float* bet = (const float*)d_in[7];

    int E  = in_sizes[2];
    int Nn = in_sizes[0] / FD;
    int nrows = Nn * TF;
    int n4 = nrows * FD / 4;
    float inv_count = 1.0f / (float)nrows;
    float* out = (float*)d_out;

    size_t idxInts = (size_t)(3 * Nn + 4);       // counts, cursor, rowptr(+pad)
    // bf16 path: idx + ssrc(E) + wsb(4E u32) + hb0(128N u32) + hb1(128N u32)
    //            + stats(3*2048 f32) + coef(3*64 f32)
    size_t needW = (idxInts + (size_t)E + 4 * (size_t)E + 128 * (size_t)Nn * 2
                    + 3 * 2048 + 3 * 64) * 4;

    int eb = (E + 255) / 256;

    if (ws_size >= needW) {
        int*          counts = (int*)d_ws;
        int*          cursor = counts + Nn;
        int*          rowptr = cursor + Nn;
        int*          ssrc   = counts + idxInts;
        uint4*        wsb    = (uint4*)(ssrc + E);
        unsigned int* hb0    = (unsigned int*)(wsb + E);       // N*128 u32
        unsigned int* hb1    = hb0 + (size_t)Nn * 128;
        float*        stats  = (float*)(hb1 + (size_t)Nn * 128);
        float*        coef   = stats + 3 * 2048;

        hipMemsetAsync(counts, 0, (size_t)Nn * sizeof(int), stream);
        hipMemsetAsync(stats, 0, 3 * 2048 * sizeof(float), stream);
        hist_kernel<<<eb, 256, 0, stream>>>(dst, counts, E);
        scan_kernel<<<1, 1024, 0, stream>>>(counts, rowptr, cursor, Nn);
        fillA_kernel<<<eb, 256, 0, stream>>>(src, dst, wgt, cursor, ssrc, wsb, E);

        // L0: nf(f32) -> hb0 (bf16 raw)
        agg_gemm3_kernel<0, 1><<<Nn, 256, 0, stream>>>(
            nf, nullptr, nullptr, rowptr, ssrc, wsb, Ws, bs,
            hb0, nullptr, stats);
        finalize_kernel<<<1, 32, 0, stream>>>(stats, gam, bet, coef, inv_count);
        // L1: hb0 -> hb1 (bf16 raw), norm0 on the fly
        agg_gemm3_kernel<1, 1><<<Nn, 256, 0, stream>>>(
            nullptr, (const uint4*)hb0, coef, rowptr, ssrc, wsb,
            Ws + FD * FD, bs + FD, hb1, nullptr, stats + 2048);
        finalize_kernel<<<1, 32, 0, stream>>>(
            stats + 2048, gam + FD, bet + FD, coef + 64, inv_count);
        // L2: hb1 -> d_out (f32 raw), norm1 on the fly
        agg_gemm3_kernel<1, 0><<<Nn, 256, 0, stream>>>(
            nullptr, (const uint4*)hb1, coef + 64, rowptr, ssrc, wsb,
            Ws + 2 * FD * FD, bs + 2 * FD, nullptr, out, stats + 2 * 2048);
        finalize_kernel<<<1, 32, 0, stream>>>(
            stats + 2 * 2048, gam + 2 * FD, bet + 2 * FD, coef + 2 * 64, inv_count);
        norm_relu_kernel<<<(n4 + 255) / 256, 256, 0, stream>>>(out, coef + 2 * 64, n4);
    } else {
        // fallback: round-0 atomic scatter path (proven)
        float* agg   = (float*)d_ws;
        float* stats = agg + (size_t)nrows * FD;
        float* coef  = stats + 2048;
        int scatterBlocks = (E * 32 + 255) / 256;
        for (int l = 0; l < 3; ++l) {
            hipMemsetAsync(agg, 0, (size_t)nrows * FD * sizeof(float), stream);
            hipMemsetAsync(stats, 0, 2048 * sizeof(float), stream);
            if (l == 0)
                scatter0_kernel<<<scatterBlocks, 256, 0, stream>>>(nf, wgt, src, dst, agg, E);
            else
                scatterL_kernel<<<scatterBlocks, 256, 0, stream>>>(out, wgt, src, dst, agg, E);
            gemm_stats_kernel<<<2048, 256, 0, stream>>>(
                agg, Ws + l * FD * FD, bs + l * FD, out, stats, nrows);
            finalize_kernel<<<1, 32, 0, stream>>>(
                stats, gam + l * FD, bet + l * FD, coef, inv_count);
            norm_relu_kernel<<<(n4 + 255) / 256, 256, 0, stream>>>(out, coef, n4);
        }
    }
}